// Round 9
// baseline (479.220 us; speedup 1.0000x reference)
//
#include <hip/hip_runtime.h>

// ---------------- problem constants ----------------
#define BB_   2
#define S_    2048
#define D_    2048
#define H_    16
#define DH_   128
#define ROPE_ 64
#define QP_   1024
#define KVP_  1365
#define KVPR_ 1429      // KVP + ROPE
#define KVP_PAD_ 1408   // K-pad for up-KV GEMM (44*32)
#define NKV_PAD_ 1536   // N-pad for down-proj KV slice (12*128)
#define NCOMB_ 2560     // QP_ + NKV_PAD_  (merged down-proj GEMM width)
#define MT_   4096      // B*S
#define UKV_N_ 3072     // D + H*NOPE

typedef unsigned short u16;
typedef unsigned int   u32;
typedef __attribute__((ext_vector_type(4))) u16    u16x4;
typedef __attribute__((ext_vector_type(8))) u16    u16x8;
typedef __attribute__((ext_vector_type(4))) u32    u32x4;
typedef __attribute__((ext_vector_type(8))) __bf16 bf16x8;
typedef __attribute__((ext_vector_type(4))) float  f32x4;
typedef __attribute__((ext_vector_type(16))) float f32x16;

#define NEG_BIG (-1.0e30f)
#define F32_FLAG_BITS 0x49742400u   // 1e6f as uint; uint-compare is NaN-safe

__device__ __forceinline__ float bf2f(u16 u) {
    u32 x = ((u32)u) << 16;
    return __builtin_bit_cast(float, x);
}
__device__ __forceinline__ u16 f2bf(float f) {
    u32 u = __builtin_bit_cast(u32, f);
    u32 r = u + 0x7fffu + ((u >> 16) & 1u);   // RTNE
    return (u16)(r >> 16);
}
// pack two floats to bf16 pair in a u32 (element j low half)
__device__ __forceinline__ u32 pk2(float a, float b) {
    __bf16 x = (__bf16)a, y = (__bf16)b;
    return (u32)__builtin_bit_cast(u16, x) | ((u32)__builtin_bit_cast(u16, y) << 16);
}
__device__ __forceinline__ bf16x8 ld_bf8(const u16* p) {
    u16x8 v = *(const u16x8*)p;
    return __builtin_bit_cast(bf16x8, v);
}
__device__ __forceinline__ bool flag_f32(const u32* flag) { return flag[0] > F32_FLAG_BITS; }

// async global->LDS, 16B per lane; lds dest = wave-uniform base + lane*16
__device__ __forceinline__ void async16(const void* g, void* l) {
    __builtin_amdgcn_global_load_lds(
        (const __attribute__((address_space(1))) void*)g,
        (__attribute__((address_space(3))) void*)l, 16, 0, 0);
}

// ---------------- rope tables (z=0) + dtype detect (z=1); flag pre-zeroed by memset ----------------
__global__ void rope_detect_kernel(float* __restrict__ cosT, float* __restrict__ sinT,
                                   const u16* __restrict__ q, u32* __restrict__ flag)
{
    if (blockIdx.z == 0) {
        int idx = blockIdx.x * 256 + threadIdx.x;
        if (idx >= S_ * 32) return;
        int pos = idx >> 5, i = idx & 31;
        float freq = (float)exp(-((double)i / 64.0) * log(10000.0));
        float ang = (float)pos * freq;
        cosT[idx] = (float)cos((double)ang);
        sinT[idx] = (float)sin((double)ang);
    } else {
        if (blockIdx.x >= 64) return;
        u32 m = 0;
        for (int i = blockIdx.x * 256 + threadIdx.x; i < (1 << 20); i += 64 * 256) {
            float v = fabsf(bf2f(q[i]));
            u32 b = __builtin_bit_cast(u32, v);
            m = m > b ? m : b;
        }
        #pragma unroll
        for (int off = 32; off; off >>= 1) {
            u32 o = (u32)__shfl_xor((int)m, off, 64);
            m = m > o ? m : o;
        }
        if ((threadIdx.x & 63) == 0) atomicMax(flag, m);
    }
}

// ---------------- prep: z=0 cast query, z=1 cast W_o, z=2..5 transpose+pad weights ----------------
__global__ __launch_bounds__(256) void prep_kernel(
    const void* __restrict__ query, const void* __restrict__ W_o,
    u16* __restrict__ q_bf, u16* __restrict__ wo_bf,
    const void* __restrict__ w_dq, const void* __restrict__ w_dkv,
    const void* __restrict__ w_uq, const void* __restrict__ w_ukv,
    u16* __restrict__ wcomb, u16* __restrict__ wuqT, u16* __restrict__ wukvT,
    const u32* __restrict__ flag)
{
    const int z = blockIdx.z;
    bool f32 = flag_f32(flag);
    if (z < 2) {
        const void* in; u16* out; long n;
        if (z == 0) { in = query; out = q_bf;  n = (long)MT_ * D_; }
        else        { in = W_o;   out = wo_bf; n = (long)D_ * D_; }
        long i0 = ((long)blockIdx.x * 256 + threadIdx.x) * 8;
        if (i0 >= n) return;
        u16x8 o;
        if (f32) {
            const float* p = (const float*)in + i0;
            #pragma unroll
            for (int j = 0; j < 8; j++) o[j] = f2bf(p[j]);
        } else {
            o = *(const u16x8*)((const u16*)in + i0);
        }
        *(u16x8*)(out + i0) = o;
        return;
    }
    // transpose+pad: out[n,k] = (k<Rin && n<Cin) ? bf16(in[k,n]) : 0
    const void* in; u16* out; int Rin, Cin, Nout, Kpad, gx, gy;
    switch (z - 2) {
        case 0: in = w_dq;  out = wcomb;                       Rin = 2048; Cin = 1024;   Nout = 1024;     Kpad = 2048;     gx = 64; gy = 32; break;
        case 1: in = w_dkv; out = wcomb + (size_t)1024 * 2048; Rin = 2048; Cin = KVPR_;  Nout = NKV_PAD_; Kpad = 2048;     gx = 64; gy = 48; break;
        case 2: in = w_uq;  out = wuqT;                        Rin = 1024; Cin = 2048;   Nout = 2048;     Kpad = 1024;     gx = 32; gy = 64; break;
        default:in = w_ukv; out = wukvT;                       Rin = KVP_; Cin = UKV_N_; Nout = UKV_N_;   Kpad = KVP_PAD_; gx = 44; gy = 96; break;
    }
    int bx = (int)blockIdx.x & 63, by = (int)blockIdx.x >> 6;
    if (bx >= gx || by >= gy) return;
    __shared__ u16 t[32][33];
    int k0 = bx * 32, n0 = by * 32;
    int tx = threadIdx.x & 31, ty = threadIdx.x >> 5;
    #pragma unroll
    for (int rr = 0; rr < 4; ++rr) {
        int k = k0 + ty + rr * 8, n = n0 + tx;
        u16 v = 0;
        if (k < Rin && n < Cin)
            v = f32 ? f2bf(((const float*)in)[(long)k * Cin + n])
                    : ((const u16*)in)[(long)k * Cin + n];
        t[ty + rr * 8][tx] = v;
    }
    __syncthreads();
    #pragma unroll
    for (int rr = 0; rr < 4; ++rr) {
        int n = n0 + ty + rr * 8, k = k0 + tx;
        if (n < Nout && k < Kpad) out[(long)n * Kpad + k] = t[tx][ty + rr * 8];
    }
}

// ---------------- GEMM core: C(4096,N) = A @ Bt^T, bf16 in, fp32 acc ----------------
// 2-phase prefetch, double-buffered LDS (passed in), one barrier per K-step. K%64==0.
// IDENTITY tile mapping (m0 = blockIdx.x*128, n0 = yt*128): consecutive bids share
// one B-panel per y-stripe (~0.5 MiB) + <=4 A-panels/XCD (<=2 MiB) => fits 4 MiB
// per-XCD L2. (r8's chunked swizzle put 8 A-panels/XCD/step = 4 MiB+B > L2 and
// regressed; reverted.)
// MODE 0: bf16 C.  MODE 2: C dtype per flag.
// MODE 3: fused rope+pack -> qh (N==2048, h = yt).
// MODE 4: split per column c: h=c/192, dd=c%192; dd<64 -> kh[b,h,s,dd], else KV V-region.
template <int MODE>
__device__ __forceinline__ void gemm_core(
    u16 (*As)[128 * 32], u16 (*Bs)[128 * 32],
    const u16* __restrict__ A, const u16* __restrict__ Bt, void* __restrict__ Cout,
    int yt, int N, int K,
    const float* __restrict__ cosT, const float* __restrict__ sinT,
    u16* __restrict__ khp, const u32* __restrict__ flag)
{
    const int tid  = threadIdx.x;
    const int lane = tid & 63;
    const int wave = tid >> 6;

    const int m0 = (int)blockIdx.x * 128;
    const int n0 = yt * 128;

    const int wr = (wave >> 1) * 64;
    const int wc = (wave & 1) * 64;
    const bool f32o = (MODE == 2) ? flag_f32(flag) : false;

    const int srow = lane >> 2;          // 0..15
    const int scol = (lane & 3) * 8;     // 0,8,16,24
    const u16* aptr0 = A  + (long)(m0 + wave * 32 + srow) * K + scol;
    const u16* bptr0 = Bt + (long)(n0 + wave * 32 + srow) * K + scol;
    const int woff = (wave * 32) * 32;

    f32x4 acc[4][4] = {};

    const int row16 = lane & 15;
    const int kq = (lane >> 4) * 8;

    auto stage = [&](int buf, int kt) {
        u16* asl = &As[buf][woff];
        u16* bsl = &Bs[buf][woff];
        async16(aptr0 + kt,          asl);
        async16(aptr0 + 16 * K + kt, asl + 16 * 32);
        async16(bptr0 + kt,          bsl);
        async16(bptr0 + 16 * K + kt, bsl + 16 * 32);
    };
    auto compute = [&](int buf) {
        bf16x8 a[4], b[4];
        #pragma unroll
        for (int i = 0; i < 4; i++)
            a[i] = ld_bf8(&As[buf][(wr + i * 16 + row16) * 32 + kq]);
        #pragma unroll
        for (int j = 0; j < 4; j++)
            b[j] = ld_bf8(&Bs[buf][(wc + j * 16 + row16) * 32 + kq]);
        #pragma unroll
        for (int i = 0; i < 4; i++)
            #pragma unroll
            for (int j = 0; j < 4; j++)
                acc[i][j] = __builtin_amdgcn_mfma_f32_16x16x32_bf16(a[i], b[j], acc[i][j], 0, 0, 0);
    };

    stage(0, 0);
    __syncthreads();                       // drains vmcnt: tile 0 ready
    const int nk = K >> 5;                 // even at all call sites
    for (int t = 0; t < nk; t += 2) {
        stage(1, (t + 1) * 32);            // prefetch odd tile
        compute(0);
        __syncthreads();                   // drain: odd tile ready; evens reads done
        if (t + 2 < nk) stage(0, (t + 2) * 32);
        compute(1);
        __syncthreads();
    }

    const int crow = wr + (lane >> 4) * 4;
    const int ccol = wc + row16;

    if (MODE == 3) {
        // qh[(b*16+h)*2048+s][d]; h = yt (N==2048). wc==64 half gets rope.
        const int h = yt;
        u16* qhp = (u16*)Cout;
        #pragma unroll
        for (int i = 0; i < 4; i++) {
            #pragma unroll
            for (int rr = 0; rr < 4; rr++) {
                int row = m0 + crow + i * 16 + rr;
                int b = row >> 11, s = row & 2047;
                long obase = (((long)(b * 16 + h)) * 2048 + s) * 128;
                if (wc == 0) {
                    #pragma unroll
                    for (int j = 0; j < 4; j++)
                        qhp[obase + j * 16 + row16] = f2bf(acc[i][j][rr]);
                } else {
                    float c0 = cosT[s * 32 + row16],      s0 = sinT[s * 32 + row16];
                    float c1 = cosT[s * 32 + 16 + row16], s1 = sinT[s * 32 + 16 + row16];
                    float x0v = acc[i][0][rr], x1v = acc[i][1][rr];
                    float x2v = acc[i][2][rr], x3v = acc[i][3][rr];
                    qhp[obase + 64 + row16]  = f2bf(x0v * c0 - x2v * s0);
                    qhp[obase + 80 + row16]  = f2bf(x1v * c1 - x3v * s1);
                    qhp[obase + 96 + row16]  = f2bf(x2v * c0 + x0v * s0);
                    qhp[obase + 112 + row16] = f2bf(x3v * c1 + x1v * s1);
                }
            }
        }
        return;
    }
    if (MODE == 4) {
        #pragma unroll
        for (int i = 0; i < 4; i++) {
            #pragma unroll
            for (int rr = 0; rr < 4; rr++) {
                int row = m0 + crow + i * 16 + rr;
                int b = row >> 11, s = row & 2047;
                #pragma unroll
                for (int j = 0; j < 4; j++) {
                    int c = n0 + wc + j * 16 + row16;
                    int h = c / 192, dd = c - h * 192;
                    u16 v16 = f2bf(acc[i][j][rr]);
                    if (dd < 64)
                        khp[(((long)(b * 16 + h)) * 2048 + s) * 128 + dd] = v16;
                    else
                        ((u16*)Cout)[(long)row * N + c] = v16;
                }
            }
        }
        return;
    }

    #pragma unroll
    for (int i = 0; i < 4; i++) {
        #pragma unroll
        for (int rr = 0; rr < 4; rr++) {
            long row = m0 + crow + i * 16 + rr;
            #pragma unroll
            for (int j = 0; j < 4; j++) {
                float v = acc[i][j][rr];
                long col = n0 + ccol + j * 16;
                if (MODE == 2 && f32o) ((float*)Cout)[row * N + col] = v;
                else                   ((u16*)Cout)[row * N + col] = f2bf(v);
            }
        }
    }
}

__global__ __launch_bounds__(256) void gemm_down_kernel(
    const u16* __restrict__ A, const u16* __restrict__ Bt, u16* __restrict__ C,
    const u32* __restrict__ flag)
{
    __shared__ u16 As[2][128 * 32];
    __shared__ u16 Bs[2][128 * 32];
    gemm_core<0>(As, Bs, A, Bt, C, (int)blockIdx.y, NCOMB_, D_, nullptr, nullptr, nullptr, flag);
}

// merged up-projections, flat grid (32,40): y<16 Q-up (rope+pack -> qh),
// y>=16 KV-up (Kn->kh, V->KV) with yt = y-16.
__global__ __launch_bounds__(256) void gemm_up_kernel(
    const u16* __restrict__ cq, const u16* __restrict__ WuqT, u16* __restrict__ qh,
    const u16* __restrict__ kv_lat, const u16* __restrict__ WukvT, u16* __restrict__ KV,
    u16* __restrict__ kh, const float* __restrict__ cosT, const float* __restrict__ sinT,
    const u32* __restrict__ flag)
{
    __shared__ u16 As[2][128 * 32];
    __shared__ u16 Bs[2][128 * 32];
    const int y = (int)blockIdx.y;
    if (y < 16) {
        gemm_core<3>(As, Bs, cq, WuqT, qh, y, 2048, QP_, cosT, sinT, nullptr, flag);
    } else {
        gemm_core<4>(As, Bs, kv_lat, WukvT, KV, y - 16, UKV_N_, KVP_PAD_, nullptr, nullptr, kh, flag);
    }
}

__global__ __launch_bounds__(256) void gemm_out_kernel(
    const u16* __restrict__ A, const u16* __restrict__ Bt, void* __restrict__ C,
    const u32* __restrict__ flag)
{
    __shared__ u16 As[2][128 * 32];
    __shared__ u16 Bs[2][128 * 32];
    gemm_core<2>(As, Bs, A, Bt, C, (int)blockIdx.y, D_, D_, nullptr, nullptr, nullptr, flag);
}

// ---------------- block reduction ----------------
__device__ __forceinline__ float block_sum(float v, float* red) {
    #pragma unroll
    for (int off = 32; off; off >>= 1) v += __shfl_xor(v, off, 64);
    int wv = threadIdx.x >> 6;
    __syncthreads();
    if ((threadIdx.x & 63) == 0) red[wv] = v;
    __syncthreads();
    return red[0] + red[1] + red[2] + red[3];
}

// ---------------- merged LN: z=0 ln_q (cqkv cols [0,1024) -> cq),
// z=1 ln_kv (cols [1024,2560): LN -> kv_lat, out1 -> d_out, roped Kr -> kh all heads)
__global__ __launch_bounds__(256) void ln_both_kernel(
    const u16* __restrict__ x, const void* __restrict__ qw, const void* __restrict__ qb,
    const void* __restrict__ kw, const void* __restrict__ kb,
    u16* __restrict__ cq, u16* __restrict__ kv_lat, void* __restrict__ d_out,
    u16* __restrict__ kh, const float* __restrict__ cosT, const float* __restrict__ sinT,
    const u32* __restrict__ flag)
{
    __shared__ float red[4];
    __shared__ float kr[64];
    bool f32 = flag_f32(flag);
    long row = blockIdx.x;
    const int tid = threadIdx.x;

    if (blockIdx.z == 0) {
        const u16* xr = x + row * NCOMB_;
        float v[4]; float s = 0.f;
        #pragma unroll
        for (int i = 0; i < 4; i++) { v[i] = bf2f(xr[tid + i * 256]); s += v[i]; }
        float mean = block_sum(s, red) * (1.0f / QP_);
        float var = 0.f;
        #pragma unroll
        for (int i = 0; i < 4; i++) { float d = v[i] - mean; var += d * d; }
        var = block_sum(var, red) * (1.0f / QP_);
        float rstd = rsqrtf(var + 1e-5f);
        #pragma unroll
        for (int i = 0; i < 4; i++) {
            int idx = tid + i * 256;
            float wv = f32 ? ((const float*)qw)[idx] : bf2f(((const u16*)qw)[idx]);
            float bv = f32 ? ((const float*)qb)[idx] : bf2f(((const u16*)qb)[idx]);
            cq[row * QP_ + idx] = f2bf((v[i] - mean) * rstd * wv + bv);
        }
    } else {
        const int b = (int)(row >> 11), s_ = (int)(row & 2047);
        const u16* xr = x + row * NCOMB_ + QP_;
        u16 u[6]; float v[6]; float s = 0.f;
        #pragma unroll
        for (int i = 0; i < 6; i++) {
            int idx = tid + i * 256;
            u[i] = xr[idx];
            v[i] = bf2f(u[i]);
            if (idx >= KVP_ && idx < KVPR_) kr[idx - KVP_] = v[i];
            if (idx < KVP_) s += v[i];
        }
        float mean = block_sum(s, red) * (1.0f / KVP_);   // barrier inside makes kr visible
        float var = 0.f;
        #pragma unroll
        for (int i = 0; i < 6; i++) {
            int idx = tid + i * 256;
            if (idx < KVP_) { float d = v[i] - mean; var += d * d; }
        }
        var = block_sum(var, red) * (1.0f / KVP_);
        float rstd = rsqrtf(var + 1e-5f);

        float* out1f = (float*)d_out + (size_t)MT_ * D_;
        u16*   out1h = (u16*)d_out   + (size_t)MT_ * D_;
        #pragma unroll
        for (int i = 0; i < 6; i++) {
            int idx = tid + i * 256;
            if (idx < KVPR_) {
                if (f32) out1f[row * KVPR_ + idx] = v[i];
                else     out1h[row * KVPR_ + idx] = u[i];
            }
            if (idx < KVP_PAD_) {
                float wv = 0.f, bv = 0.f;
                if (idx < KVP_) {
                    wv = f32 ? ((const float*)kw)[idx] : bf2f(((const u16*)kw)[idx]);
                    bv = f32 ? ((const float*)kb)[idx] : bf2f(((const u16*)kb)[idx]);
                }
                u16 o = 0;
                if (idx < KVP_) o = f2bf((v[i] - mean) * rstd * wv + bv);
                kv_lat[row * KVP_PAD_ + idx] = o;
            }
            // roped Kr broadcast to all 16 heads (kh d in [64,128))
            if (idx >= KVP_ && idx < KVPR_) {
                int r = idx - KVP_;
                float xr_ = kr[r];
                float xo = (r < 32) ? -kr[r + 32] : kr[r - 32];
                int m = r & 31;
                u16 vv = f2bf(xr_ * cosT[s_ * 32 + m] + xo * sinT[s_ * 32 + m]);
                #pragma unroll
                for (int h = 0; h < 16; h++)
                    kh[(((long)(b * 16 + h)) * 2048 + s_) * 128 + 64 + r] = vv;
            }
        }
    }
}

// ---------------- Vt(b,h,d,s) <- KV(b,s, h*192+64+d) ----------------
__global__ __launch_bounds__(256) void pack_vt_kernel(const u16* __restrict__ KV, u16* __restrict__ Vt)
{
    int bh = blockIdx.x; int b = bh >> 4, h = bh & 15;
    int s0 = blockIdx.y * 64;
    __shared__ u16 t[64][136];
    #pragma unroll
    for (int it = 0; it < 4; ++it) {
        int ch = threadIdx.x + it * 256;
        int sr = ch >> 4, c8 = (ch & 15) * 8;
        *(u16x8*)&t[sr][c8] = *(const u16x8*)&KV[((long)(b * S_ + s0 + sr)) * 3072 + h * 192 + 64 + c8];
    }
    __syncthreads();
    #pragma unroll
    for (int it = 0; it < 4; ++it) {
        int ch = threadIdx.x + it * 256;
        int d = ch >> 3, s8 = (ch & 7) * 8;
        u16x8 v;
        #pragma unroll
        for (int j = 0; j < 8; j++) v[j] = t[s8 + j][d];
        *(u16x8*)&Vt[((long)bh * 128 + d) * S_ + s0 + s8] = v;
    }
}

// ---------------- flash attention (causal), swapped-QK 32x32 in-register-P ----------------
// 256 threads / 4 waves; Q-tile 128 (wave owns 32 q = lane&31), K-tile 64.
// Swapped QK (A=K, B=Q): lane holds S[k][q=l5] for its q-row's full 64-k slice.
// P stays in registers (pk2 + shfl_xor(32)); 32x32x16 MFMA; T14 staging; T13 defer-max.
// LOAD BALANCE: cohorts z<2 / z>=2 get complementary jq (15-y vs y) so co-resident
// block pairs sum to a constant 34 k-tiles.
#define ATT_SCALE 0.08838834764831845f
#define K_LOG2E (ATT_SCALE * 1.4426950408889634f)
#define DEFER_THR 62.0f   // raw-score slack; * K_LOG2E ~= 7.9 exp2-units

__global__ __launch_bounds__(256, 2) void attn_kernel(
    const u16* __restrict__ qh, const u16* __restrict__ kh,
    const u16* __restrict__ Vt, u16* __restrict__ attn_out)
{
    __shared__ u16 Ks[64 * 128];   // 16 KiB, swizzled: row k (256B), granule^(k&7)
    __shared__ u16 Vs[128 * 64];   // 16 KiB, swizzled: row d (128B), granule^(d&7)

    const int bh = (int)blockIdx.x + ((int)blockIdx.z << 3);
    const int b = bh >> 4, h = bh & 15;
    const int jq = ((int)blockIdx.z < 2) ? (15 - (int)blockIdx.y) : (int)blockIdx.y;
    const int qbase = jq * 128;
    const int tid = threadIdx.x;
    const int lane = tid & 63;
    const int w = tid >> 6;        // 0..3
    const int l5 = lane & 31;
    const int hi = lane >> 5;
    const int wq0 = qbase + w * 32;
    const int qg = wq0 + l5;       // this lane's q-row
    const int kend = qbase + 128;
    const int kend_w = wq0 + 32;   // wave's causal limit

    // Q as B-fragments: lane holds Q[q=qg][d = kc*16 + 8*hi + j]
    bf16x8 qb[8];
    {
        const u16* qp = &qh[((long)bh * S_ + qg) * 128 + 8 * hi];
        #pragma unroll
        for (int kc = 0; kc < 8; kc++)
            qb[kc] = ld_bf8(qp + kc * 16);
    }

    f32x16 o[4] = {};     // O[d = dt*32 + (reg&3)+8*(reg>>2)+4*hi][q=qg]
    float m_run = NEG_BIG;
    float l_run = 0.f;

    const long khb = (long)bh * S_;

    // T14 staging regs: wave w loads K rows [w*16,+16), V^T d-rows [w*32,+32)
    u16x8 kst[4], vst[4];
    auto load_kv = [&](int k0) {
        #pragma unroll
        for (int it = 0; it < 4; ++it) {
            int r = w * 16 + it * 4 + (lane >> 4);
            kst[it] = *(const u16x8*)&kh[(khb + k0 + r) * 128 + (((lane & 15) ^ (r & 7)) << 3)];
        }
        #pragma unroll
        for (int it = 0; it < 4; ++it) {
            int d = w * 32 + it * 8 + (lane >> 3);
            vst[it] = *(const u16x8*)&Vt[((long)bh * 128 + d) * S_ + k0 + (((lane & 7) ^ (d & 7)) << 3)];
        }
    };

    load_kv(0);

    for (int k0 = 0; k0 < kend; k0 += 64) {
        __syncthreads();   // prev iter's LDS reads done
        #pragma unroll
        for (int it = 0; it < 4; ++it)
            *(u16x8*)&Ks[(w * 16 + it * 4) * 128 + lane * 8] = kst[it];
        #pragma unroll
        for (int it = 0; it < 4; ++it)
            *(u16x8*)&Vs[(w * 32 + it * 8) * 64 + lane * 8] = vst[it];
        __syncthreads();   // tiles visible
        if (k0 + 64 < kend) load_kv(k0 + 64);   // next tile flies under compute

        if (k0 < kend_w) {   // wave-uniform causal skip
            // ---- QK^T swapped: S[k][q], A = K rows, B = Q ----
            f32x16 sc[2] = {};
            #pragma unroll
            for (int kc = 0; kc < 8; kc++) {
                #pragma unroll
                for (int ct = 0; ct < 2; ct++) {
                    int krow = ct * 32 + l5;
                    bf16x8 kf = ld_bf8(&Ks[krow * 128 + (((2 * kc + hi) ^ (krow & 7)) << 3)]);
                    sc[ct] = __builtin_amdgcn_mfma_f32_32x32x16_bf16(kf, qb[kc], sc[ct], 0, 0, 0);
                }
            }
            // ---- causal mask (k = k0 + ct*32 + t + 8g + 4hi; col q = qg) ----
            if (k0 + 64 > wq0) {
                #pragma unroll
                for (int ct = 0; ct < 2; ct++)
                    #pragma unroll
                    for (int g = 0; g < 4; g++)
                        #pragma unroll
                        for (int t = 0; t < 4; t++)
                            sc[ct][g * 4 + t] =
                                (k0 + ct * 32 + g * 8 + t + 4 * hi <= qg) ? sc[ct][g * 4 + t] : NEG_BIG;
            }
            // ---- row max: 31 in-lane fmax + cross-half ----
            float m = sc[0][0];
            #pragma unroll
            for (int i = 1; i < 16; i++) m = fmaxf(m, sc[0][i]);
            #pragma unroll
            for (int i = 0; i < 16; i++) m = fmaxf(m, sc[1][i]);
            m = fmaxf(m, __shfl_xor(m, 32, 64));
            // ---- defer-max (T13): rescale only when some row grew >THR ----
            bool ok = (m <= m_run + DEFER_THR);
            if (!__all((int)ok)) {
                float mn = fmaxf(m_run, m);
                float alpha = exp2f((m_run - mn) * K_LOG2E);
                m_run = mn;
                l_run *= alpha;
                #pragma unroll
                for (int dt = 0; dt < 4; dt++)
                    #pragma unroll
                    for (int i = 0; i < 16; i++) o[dt][i] *= alpha;
            }
            // ---- P = exp2((S - m_run)*c) in place; in-lane sum ----
            float mk = m_run * K_LOG2E;
            float s = 0.f;
            #pragma unroll
            for (int ct = 0; ct < 2; ct++)
                #pragma unroll
                for (int i = 0; i < 16; i++) {
                    float p = exp2f(fmaf(sc[ct][i], K_LOG2E, -mk));
                    sc[ct][i] = p;
                    s += p;
                }
            l_run += s + __shfl_xor(s, 32, 64);
            // ---- build PV B-frags pb[kk = ct*2+c2]: lane needs P[k=c2*16+8hi+j][qg].
            bf16x8 pb[4];
            #pragma unroll
            for (int ct = 0; ct < 2; ct++)
                #pragma unroll
                for (int c2 = 0; c2 < 2; c2++) {
                    u32 lo0 = pk2(sc[ct][8 * c2 + 0], sc[ct][8 * c2 + 1]);
                    u32 lo1 = pk2(sc[ct][8 * c2 + 2], sc[ct][8 * c2 + 3]);
                    u32 h0  = pk2(sc[ct][8 * c2 + 4], sc[ct][8 * c2 + 5]);
                    u32 h1  = pk2(sc[ct][8 * c2 + 6], sc[ct][8 * c2 + 7]);
                    u32 s0 = hi ? lo0 : h0;
                    u32 s1 = hi ? lo1 : h1;
                    u32 r0 = (u32)__shfl_xor((int)s0, 32, 64);
                    u32 r1 = (u32)__shfl_xor((int)s1, 32, 64);
                    u32x4 f;
                    f[0] = hi ? r0 : lo0;
                    f[1] = hi ? r1 : lo1;
                    f[2] = hi ? h0 : r0;
                    f[3] = hi ? h1 : r1;
                    pb[ct * 2 + c2] = __builtin_bit_cast(bf16x8, f);
                }
            // ---- PV: O[d][q] += V^T[d][k] * P[k][q]; A = V^T rows ----
            #pragma unroll
            for (int kk = 0; kk < 4; kk++) {
                #pragma unroll
                for (int dt = 0; dt < 4; dt++) {
                    int drow = dt * 32 + l5;
                    bf16x8 vf = ld_bf8(&Vs[drow * 64 + (((2 * kk + hi) ^ (drow & 7)) << 3)]);
                    o[dt] = __builtin_amdgcn_mfma_f32_32x32x16_bf16(vf, pb[kk], o[dt], 0, 0, 0);
                }
            }
        }
    }

    // ---- epilogue: out[q=qg][d] = o/l; d = dt*32 + 8g + 4hi + t ----
    float inv = 1.0f / l_run;
    const long orow = ((long)b * S_ + qg) * 2048 + h * 128;
    #pragma unroll
    for (int dt = 0; dt < 4; dt++)
        #pragma unroll
        for (int g = 0; g < 4; g++) {
            u16x4 v;
            #pragma unroll
            for (int t = 0; t < 4; t++) v[t] = f2bf(o[dt][g * 4 + t] * inv);
            *(u16x4*)&attn_out[orow + dt * 32 + g * 8 + 4 * hi] = v;
        }
}

// ---------------- launch ----------------
#define MIB(x) ((size_t)(x) << 20)
extern "C" void kernel_launch(void* const* d_in, const int* in_sizes, int n_in,
                              void* d_out, int out_size, void* d_ws, size_t ws_size,
                              hipStream_t stream)
{
    const void* query  = d_in[0];
    const void* W_dq   = d_in[1];
    const void* W_uq   = d_in[2];
    const void* q_ln_w = d_in[3];
    const void* q_ln_b = d_in[4];
    const void* W_dkv  = d_in[5];
    const void* W_ukv  = d_in[6];
    const void* kv_ln_w = d_in[7];
    const void* kv_ln_b = d_in[8];
    const void* W_o    = d_in[9];
    (void)ws_size; (void)in_sizes; (void)n_in; (void)out_size;

    char* base = (char*)d_ws;
    u32*   flag     = (u32*)base;                         // 4 B (+pad)
    float* rope_cos = (float*)(base + 4096);              // 256 KiB
    float* rope_sin = (float*)(base + 266240);            // 256 KiB
    u16* qh     = (u16*)(base + MIB(1));                  // 16 MiB
    u16* kh     = (u16*)(base + MIB(17));                 // 16 MiB
    u16* Vt     = (u16*)(base + MIB(33));                 // 16 MiB
    u16* q_bf   = (u16*)(base + MIB(49));                 // 16 MiB
    u16* Wo_bf  = (u16*)(base + MIB(65));                 // 8 MiB
    // scratch (lifetimes): peak 134.25 MiB
    u16* Wcomb  = (u16*)(base + MIB(73));                 // 10 MiB  (prep -> gemm_down)
    u16* cqkv   = (u16*)(base + MIB(83));                 // 20 MiB  (gemm_down -> LNs)
    u16* cq     = (u16*)(base + MIB(103));                // 8 MiB   (ln -> gemm_up y<16)
    u16* kv_lat = (u16*)(base + MIB(111));                // 11 MiB  (ln -> gemm_up y>=16)
    u16* WuqT   = (u16*)(base + MIB(122));                // 4 MiB
    u16* WukvT  = (u16*)(base + MIB(126));                // 8.25 MiB -> 134.25
    u16* KV     = (u16*)(base + MIB(73));                 // 24 MiB  (gemm_up -> pack_vt; Wcomb/cqkv-head dead)
    u16* attn_o = (u16*)(base + MIB(73));                 // 16 MiB  (attn -> gemm_out; KV dead)

    hipMemsetAsync(flag, 0, sizeof(u32), stream);
    rope_detect_kernel<<<dim3(256, 1, 2), 256, 0, stream>>>(rope_cos, rope_sin,
                                                            (const u16*)query, flag);
    prep_kernel<<<dim3(6144, 1, 6), 256, 0, stream>>>(query, W_o, q_bf, Wo_bf,
                                                      W_dq, W_dkv, W_uq, W_ukv,
                                                      Wcomb, WuqT, WukvT, flag);

    // ---- merged down-projection GEMM ----
    gemm_down_kernel<<<dim3(32, 20), 256, 0, stream>>>(q_bf, Wcomb, cqkv, flag);
    // ---- both LayerNorms (z=0: q, z=1: kv + out1 + roped-Kr broadcast into kh) ----
    ln_both_kernel<<<dim3(MT_, 1, 2), 256, 0, stream>>>(cqkv, q_ln_w, q_ln_b, kv_ln_w, kv_ln_b,
                                                        cq, kv_lat, d_out, kh,
                                                        rope_cos, rope_sin, flag);
    // ---- merged up-projections, flat grid (y<16: Q rope+pack -> qh; y>=16: KV -> kh/KV) ----
    gemm_up_kernel<<<dim3(32, 40), 256, 0, stream>>>(cq, WuqT, qh, kv_lat, WukvT, KV, kh,
                                                     rope_cos, rope_sin, flag);
    pack_vt_kernel<<<dim3(32, 32), 256, 0, stream>>>(KV, Vt);

    // ---- attention + out projection ----
    attn_kernel<<<dim3(8, 16, 4), 256, 0, stream>>>(qh, kh, Vt, attn_o);
    gemm_out_kernel<<<dim3(32, 16), 256, 0, stream>>>(attn_o, Wo_bf, d_out, flag);
}

// Round 10
// 458.184 us; speedup vs baseline: 1.0459x; 1.0459x over previous
//
#include <hip/hip_runtime.h>

// ---------------- problem constants ----------------
#define BB_   2
#define S_    2048
#define D_    2048
#define H_    16
#define DH_   128
#define ROPE_ 64
#define QP_   1024
#define KVP_  1365
#define KVPR_ 1429      // KVP + ROPE
#define KVP_PAD_ 1408   // K-pad for up-KV GEMM (44*32)
#define NKV_PAD_ 1536   // N-pad for down-proj KV slice (12*128)
#define NCOMB_ 2560     // QP_ + NKV_PAD_  (merged down-proj GEMM width)
#define MT_   4096      // B*S
#define UKV_N_ 3072     // D + H*NOPE

typedef unsigned short u16;
typedef unsigned int   u32;
typedef __attribute__((ext_vector_type(4))) u16    u16x4;
typedef __attribute__((ext_vector_type(8))) u16    u16x8;
typedef __attribute__((ext_vector_type(4))) u32    u32x4;
typedef __attribute__((ext_vector_type(8))) __bf16 bf16x8;
typedef __attribute__((ext_vector_type(4))) float  f32x4;
typedef __attribute__((ext_vector_type(16))) float f32x16;

#define NEG_BIG (-1.0e30f)
#define F32_FLAG_BITS 0x49742400u   // 1e6f as uint; uint-compare is NaN-safe

__device__ __forceinline__ float bf2f(u16 u) {
    u32 x = ((u32)u) << 16;
    return __builtin_bit_cast(float, x);
}
__device__ __forceinline__ u16 f2bf(float f) {
    u32 u = __builtin_bit_cast(u32, f);
    u32 r = u + 0x7fffu + ((u >> 16) & 1u);   // RTNE
    return (u16)(r >> 16);
}
// pack two floats to bf16 pair in a u32 (element j low half)
__device__ __forceinline__ u32 pk2(float a, float b) {
    __bf16 x = (__bf16)a, y = (__bf16)b;
    return (u32)__builtin_bit_cast(u16, x) | ((u32)__builtin_bit_cast(u16, y) << 16);
}
__device__ __forceinline__ bf16x8 ld_bf8(const u16* p) {
    u16x8 v = *(const u16x8*)p;
    return __builtin_bit_cast(bf16x8, v);
}
__device__ __forceinline__ bool flag_f32(const u32* flag) { return flag[0] > F32_FLAG_BITS; }

// async global->LDS, 16B per lane; lds dest = wave-uniform base + lane*16
__device__ __forceinline__ void async16(const void* g, void* l) {
    __builtin_amdgcn_global_load_lds(
        (const __attribute__((address_space(1))) void*)g,
        (__attribute__((address_space(3))) void*)l, 16, 0, 0);
}

// ---------------- dtype detect: max |bf16-view| of first 1M u16 of query ----------------
__global__ __launch_bounds__(256) void detect_kernel(const u16* __restrict__ q, u32* __restrict__ flag)
{
    u32 m = 0;
    for (int i = blockIdx.x * 256 + threadIdx.x; i < (1 << 20); i += 64 * 256) {
        float v = fabsf(bf2f(q[i]));
        u32 b = __builtin_bit_cast(u32, v);
        m = m > b ? m : b;
    }
    #pragma unroll
    for (int off = 32; off; off >>= 1) {
        u32 o = (u32)__shfl_xor((int)m, off, 64);
        m = m > o ? m : o;
    }
    if ((threadIdx.x & 63) == 0) atomicMax(flag, m);
}

// ---------------- merged cast: z=0 query->q_bf (8M), z=1 W_o->Wo_bf (4M) ----------------
__global__ __launch_bounds__(256) void cast_merged_kernel(
    const void* __restrict__ qin, const void* __restrict__ woin,
    u16* __restrict__ q_bf, u16* __restrict__ wo_bf, const u32* __restrict__ flag)
{
    bool f32 = flag_f32(flag);
    const void* in; u16* out; long n;
    if (blockIdx.z == 0) { in = qin;  out = q_bf;  n = (long)MT_ * D_; }
    else                 { in = woin; out = wo_bf; n = (long)D_ * D_; if (blockIdx.x >= 2048) return; }
    long i0 = ((long)blockIdx.x * 256 + threadIdx.x) * 8;
    if (i0 >= n) return;
    u16x8 o;
    if (f32) {
        const float* p = (const float*)in + i0;
        #pragma unroll
        for (int j = 0; j < 8; j++) o[j] = f2bf(p[j]);
    } else {
        o = *(const u16x8*)((const u16*)in + i0);
    }
    *(u16x8*)(out + i0) = o;
}

// ---------------- GEMM: C(M,N) = A(M,K) @ Bt(N,K)^T, bf16 in, fp32 acc ----------------
// T3/T4 counted-vmcnt pipeline: TRIPLE-buffered LDS (48 KiB), prefetch 2 K-tiles
// ahead via global_load_lds; raw s_barrier + s_waitcnt vmcnt(8) -- loads stay in
// flight ACROSS barriers (never drained to 0 in steady state). Steady state:
// 12 outstanding loads; vmcnt(8) retires exactly tile-t's 4. Tail: vmcnt(4)/(0).
// Barrier A: all waves' tile-t loads landed; Barrier B: all waves done reading
// buf[t] before iter t+1's stage overwrites buf[(t+3)%3]. (m139 precedent: raw
// barrier + vmcnt with this staging pattern is race-free.)
// MODE 0: bf16 C.  MODE 2: C dtype per flag.
// MODE 3: fused rope+pack -> qh (N==2048, h=blockIdx.y; rope pairs (j,j+2) in-thread).
// MODE 4: split per column c: h=c/192, dd=c%192; dd<64 -> kh[b,h,s,dd], else KV V-region.
template <int MODE>
__global__ __launch_bounds__(256) void gemm_bt(
    const u16* __restrict__ A, const u16* __restrict__ Bt,
    void* __restrict__ Cout, int M, int N, int K,
    const float* __restrict__ cosT, const float* __restrict__ sinT,
    u16* __restrict__ khp, const u32* __restrict__ flag)
{
    __shared__ u16 As[3][128 * 32];
    __shared__ u16 Bs[3][128 * 32];
    const int tid  = threadIdx.x;
    const int lane = tid & 63;
    const int wave = tid >> 6;
    const int m0 = blockIdx.x * 128;
    const int n0 = blockIdx.y * 128;
    const int wr = (wave >> 1) * 64;
    const int wc = (wave & 1) * 64;
    const bool f32o = (MODE == 2) ? flag_f32(flag) : false;

    const int srow = lane >> 2;          // 0..15
    const int scol = (lane & 3) * 8;     // 0,8,16,24
    const u16* aptr0 = A  + (long)(m0 + wave * 32 + srow) * K + scol;
    const u16* bptr0 = Bt + (long)(n0 + wave * 32 + srow) * K + scol;
    const int woff = (wave * 32) * 32;

    f32x4 acc[4][4] = {};

    const int row16 = lane & 15;
    const int kq = (lane >> 4) * 8;

    auto stage = [&](int buf, int kt) {
        u16* asl = &As[buf][woff];
        u16* bsl = &Bs[buf][woff];
        async16(aptr0 + kt,          asl);
        async16(aptr0 + 16 * K + kt, asl + 16 * 32);
        async16(bptr0 + kt,          bsl);
        async16(bptr0 + 16 * K + kt, bsl + 16 * 32);
    };
    auto compute = [&](int buf) {
        bf16x8 a[4], b[4];
        #pragma unroll
        for (int i = 0; i < 4; i++)
            a[i] = ld_bf8(&As[buf][(wr + i * 16 + row16) * 32 + kq]);
        #pragma unroll
        for (int j = 0; j < 4; j++)
            b[j] = ld_bf8(&Bs[buf][(wc + j * 16 + row16) * 32 + kq]);
        #pragma unroll
        for (int i = 0; i < 4; i++)
            #pragma unroll
            for (int j = 0; j < 4; j++)
                acc[i][j] = __builtin_amdgcn_mfma_f32_16x16x32_bf16(a[i], b[j], acc[i][j], 0, 0, 0);
    };

    const int nk = K >> 5;                 // >= 32 at all call sites
    stage(0, 0);
    stage(1, 32);
    int buf = 0;
    for (int t = 0; t < nk; ++t) {
        if (t + 2 < nk) {
            int nb = buf + 2; if (nb >= 3) nb -= 3;
            stage(nb, (t + 2) * 32);
            asm volatile("s_waitcnt vmcnt(8)" ::: "memory");
        } else if (t + 1 < nk) {
            asm volatile("s_waitcnt vmcnt(4)" ::: "memory");
        } else {
            asm volatile("s_waitcnt vmcnt(0)" ::: "memory");
        }
        __builtin_amdgcn_s_barrier();      // tile-t loads landed (all waves)
        compute(buf);
        __builtin_amdgcn_s_barrier();      // all waves done reading buf before overwrite
        buf = (buf + 1 == 3) ? 0 : buf + 1;
    }

    const int crow = wr + (lane >> 4) * 4;
    const int ccol = wc + row16;

    if (MODE == 3) {
        // qh[(b*16+h)*2048+s][d]; h = blockIdx.y (N==2048). wc==64 half gets rope.
        const int h = (int)blockIdx.y;
        u16* qhp = (u16*)Cout;
        #pragma unroll
        for (int i = 0; i < 4; i++) {
            #pragma unroll
            for (int rr = 0; rr < 4; rr++) {
                int row = m0 + crow + i * 16 + rr;
                int b = row >> 11, s = row & 2047;
                long obase = (((long)(b * 16 + h)) * 2048 + s) * 128;
                if (wc == 0) {
                    #pragma unroll
                    for (int j = 0; j < 4; j++)
                        qhp[obase + j * 16 + row16] = f2bf(acc[i][j][rr]);
                } else {
                    float c0 = cosT[s * 32 + row16],      s0 = sinT[s * 32 + row16];
                    float c1 = cosT[s * 32 + 16 + row16], s1 = sinT[s * 32 + 16 + row16];
                    float x0v = acc[i][0][rr], x1v = acc[i][1][rr];
                    float x2v = acc[i][2][rr], x3v = acc[i][3][rr];
                    // rope pairs: (r=row16, r+32) = (j0,j2) ; (r=16+row16, r+32) = (j1,j3)
                    qhp[obase + 64 + row16]  = f2bf(x0v * c0 - x2v * s0);
                    qhp[obase + 80 + row16]  = f2bf(x1v * c1 - x3v * s1);
                    qhp[obase + 96 + row16]  = f2bf(x2v * c0 + x0v * s0);
                    qhp[obase + 112 + row16] = f2bf(x3v * c1 + x1v * s1);
                }
            }
        }
        return;
    }
    if (MODE == 4) {
        #pragma unroll
        for (int i = 0; i < 4; i++) {
            #pragma unroll
            for (int rr = 0; rr < 4; rr++) {
                int row = m0 + crow + i * 16 + rr;
                int b = row >> 11, s = row & 2047;
                #pragma unroll
                for (int j = 0; j < 4; j++) {
                    int c = n0 + wc + j * 16 + row16;
                    int h = c / 192, dd = c - h * 192;
                    u16 v16 = f2bf(acc[i][j][rr]);
                    if (dd < 64)
                        khp[(((long)(b * 16 + h)) * 2048 + s) * 128 + dd] = v16;
                    else
                        ((u16*)Cout)[(long)row * N + c] = v16;
                }
            }
        }
        return;
    }

    #pragma unroll
    for (int i = 0; i < 4; i++) {
        #pragma unroll
        for (int rr = 0; rr < 4; rr++) {
            long row = m0 + crow + i * 16 + rr;
            #pragma unroll
            for (int j = 0; j < 4; j++) {
                float v = acc[i][j][rr];
                long col = n0 + ccol + j * 16;
                if (MODE == 2 && f32o) ((float*)Cout)[row * N + col] = v;
                else                   ((u16*)Cout)[row * N + col] = f2bf(v);
            }
        }
    }
}

// ---------------- merged transpose+pad: z selects weight ----------------
// out[n,k] = (k<Rin && n<Cin) ? bf16(in[k,n]) : 0
__global__ __launch_bounds__(256) void transpose_all_kernel(
    const void* __restrict__ w_dq, const void* __restrict__ w_dkv,
    const void* __restrict__ w_uq, const void* __restrict__ w_ukv,
    u16* __restrict__ wcomb, u16* __restrict__ wuqT, u16* __restrict__ wukvT,
    const u32* __restrict__ flag)
{
    const void* in; u16* out; int Rin, Cin, Nout, Kpad, gx, gy;
    switch (blockIdx.z) {
        case 0: in = w_dq;  out = wcomb;                       Rin = 2048; Cin = 1024;   Nout = 1024;     Kpad = 2048;     gx = 64; gy = 32; break;
        case 1: in = w_dkv; out = wcomb + (size_t)1024 * 2048; Rin = 2048; Cin = KVPR_;  Nout = NKV_PAD_; Kpad = 2048;     gx = 64; gy = 48; break;
        case 2: in = w_uq;  out = wuqT;                        Rin = 1024; Cin = 2048;   Nout = 2048;     Kpad = 1024;     gx = 32; gy = 64; break;
        default:in = w_ukv; out = wukvT;                       Rin = KVP_; Cin = UKV_N_; Nout = UKV_N_;   Kpad = KVP_PAD_; gx = 44; gy = 96; break;
    }
    if ((int)blockIdx.x >= gx || (int)blockIdx.y >= gy) return;
    __shared__ u16 t[32][33];
    bool f32 = flag_f32(flag);
    int k0 = blockIdx.x * 32, n0 = blockIdx.y * 32;
    int tx = threadIdx.x & 31, ty = threadIdx.x >> 5;
    #pragma unroll
    for (int rr = 0; rr < 4; ++rr) {
        int k = k0 + ty + rr * 8, n = n0 + tx;
        u16 v = 0;
        if (k < Rin && n < Cin)
            v = f32 ? f2bf(((const float*)in)[(long)k * Cin + n])
                    : ((const u16*)in)[(long)k * Cin + n];
        t[ty + rr * 8][tx] = v;
    }
    __syncthreads();
    #pragma unroll
    for (int rr = 0; rr < 4; ++rr) {
        int n = n0 + ty + rr * 8, k = k0 + tx;
        if (n < Nout && k < Kpad) out[(long)n * Kpad + k] = t[tx][ty + rr * 8];
    }
}

// ---------------- block reduction ----------------
__device__ __forceinline__ float block_sum(float v, float* red) {
    #pragma unroll
    for (int off = 32; off; off >>= 1) v += __shfl_xor(v, off, 64);
    int wv = threadIdx.x >> 6;
    __syncthreads();
    if ((threadIdx.x & 63) == 0) red[wv] = v;
    __syncthreads();
    return red[0] + red[1] + red[2] + red[3];
}

// ---------------- merged LN: z=0 ln_q (cqkv cols [0,1024) -> cq),
// z=1 ln_kv (cols [1024,2560): LN -> kv_lat, out1 -> d_out, roped Kr -> kh all heads)
__global__ __launch_bounds__(256) void ln_both_kernel(
    const u16* __restrict__ x, const void* __restrict__ qw, const void* __restrict__ qb,
    const void* __restrict__ kw, const void* __restrict__ kb,
    u16* __restrict__ cq, u16* __restrict__ kv_lat, void* __restrict__ d_out,
    u16* __restrict__ kh, const float* __restrict__ cosT, const float* __restrict__ sinT,
    const u32* __restrict__ flag)
{
    __shared__ float red[4];
    __shared__ float kr[64];
    bool f32 = flag_f32(flag);
    long row = blockIdx.x;
    const int tid = threadIdx.x;

    if (blockIdx.z == 0) {
        const u16* xr = x + row * NCOMB_;
        float v[4]; float s = 0.f;
        #pragma unroll
        for (int i = 0; i < 4; i++) { v[i] = bf2f(xr[tid + i * 256]); s += v[i]; }
        float mean = block_sum(s, red) * (1.0f / QP_);
        float var = 0.f;
        #pragma unroll
        for (int i = 0; i < 4; i++) { float d = v[i] - mean; var += d * d; }
        var = block_sum(var, red) * (1.0f / QP_);
        float rstd = rsqrtf(var + 1e-5f);
        #pragma unroll
        for (int i = 0; i < 4; i++) {
            int idx = tid + i * 256;
            float wv = f32 ? ((const float*)qw)[idx] : bf2f(((const u16*)qw)[idx]);
            float bv = f32 ? ((const float*)qb)[idx] : bf2f(((const u16*)qb)[idx]);
            cq[row * QP_ + idx] = f2bf((v[i] - mean) * rstd * wv + bv);
        }
    } else {
        const int b = (int)(row >> 11), s_ = (int)(row & 2047);
        const u16* xr = x + row * NCOMB_ + QP_;
        u16 u[6]; float v[6]; float s = 0.f;
        #pragma unroll
        for (int i = 0; i < 6; i++) {
            int idx = tid + i * 256;
            u[i] = xr[idx];
            v[i] = bf2f(u[i]);
            if (idx >= KVP_ && idx < KVPR_) kr[idx - KVP_] = v[i];
            if (idx < KVP_) s += v[i];
        }
        float mean = block_sum(s, red) * (1.0f / KVP_);   // barrier inside makes kr visible
        float var = 0.f;
        #pragma unroll
        for (int i = 0; i < 6; i++) {
            int idx = tid + i * 256;
            if (idx < KVP_) { float d = v[i] - mean; var += d * d; }
        }
        var = block_sum(var, red) * (1.0f / KVP_);
        float rstd = rsqrtf(var + 1e-5f);

        float* out1f = (float*)d_out + (size_t)MT_ * D_;
        u16*   out1h = (u16*)d_out   + (size_t)MT_ * D_;
        #pragma unroll
        for (int i = 0; i < 6; i++) {
            int idx = tid + i * 256;
            if (idx < KVPR_) {
                if (f32) out1f[row * KVPR_ + idx] = v[i];
                else     out1h[row * KVPR_ + idx] = u[i];
            }
            if (idx < KVP_PAD_) {
                float wv = 0.f, bv = 0.f;
                if (idx < KVP_) {
                    wv = f32 ? ((const float*)kw)[idx] : bf2f(((const u16*)kw)[idx]);
                    bv = f32 ? ((const float*)kb)[idx] : bf2f(((const u16*)kb)[idx]);
                }
                u16 o = 0;
                if (idx < KVP_) o = f2bf((v[i] - mean) * rstd * wv + bv);
                kv_lat[row * KVP_PAD_ + idx] = o;
            }
            // roped Kr broadcast to all 16 heads (kh d in [64,128))
            if (idx >= KVP_ && idx < KVPR_) {
                int r = idx - KVP_;
                float xr_ = kr[r];
                float xo = (r < 32) ? -kr[r + 32] : kr[r - 32];
                int m = r & 31;
                u16 vv = f2bf(xr_ * cosT[s_ * 32 + m] + xo * sinT[s_ * 32 + m]);
                #pragma unroll
                for (int h = 0; h < 16; h++)
                    kh[(((long)(b * 16 + h)) * 2048 + s_) * 128 + 64 + r] = vv;
            }
        }
    }
}

// ---------------- rope tables (S x 32) + flag init ----------------
__global__ void rope_tab_kernel(float* __restrict__ cosT, float* __restrict__ sinT, u32* __restrict__ flag) {
    int idx = blockIdx.x * 256 + threadIdx.x;
    if (idx == 0) flag[0] = 0u;   // runs in a prior dispatch than detect_kernel
    if (idx >= S_ * 32) return;
    int pos = idx >> 5, i = idx & 31;
    float freq = (float)exp(-((double)i / 64.0) * log(10000.0));
    float ang = (float)pos * freq;
    cosT[idx] = (float)cos((double)ang);
    sinT[idx] = (float)sin((double)ang);
}

// ---------------- Vt(b,h,d,s) <- KV(b,s, h*192+64+d) ----------------
__global__ __launch_bounds__(256) void pack_vt_kernel(const u16* __restrict__ KV, u16* __restrict__ Vt)
{
    int bh = blockIdx.x; int b = bh >> 4, h = bh & 15;
    int s0 = blockIdx.y * 64;
    __shared__ u16 t[64][136];
    #pragma unroll
    for (int it = 0; it < 4; ++it) {
        int ch = threadIdx.x + it * 256;
        int sr = ch >> 4, c8 = (ch & 15) * 8;
        *(u16x8*)&t[sr][c8] = *(const u16x8*)&KV[((long)(b * S_ + s0 + sr)) * 3072 + h * 192 + 64 + c8];
    }
    __syncthreads();
    #pragma unroll
    for (int it = 0; it < 4; ++it) {
        int ch = threadIdx.x + it * 256;
        int d = ch >> 3, s8 = (ch & 7) * 8;
        u16x8 v;
        #pragma unroll
        for (int j = 0; j < 8; j++) v[j] = t[s8 + j][d];
        *(u16x8*)&Vt[((long)bh * 128 + d) * S_ + s0 + s8] = v;
    }
}

// ---------------- flash attention (causal), swapped-QK 32x32 in-register-P ----------------
// 256 threads / 4 waves; Q-tile 128 (wave owns 32 q = lane&31), K-tile 64.
// Swapped QK (A=K, B=Q): lane holds S[k][q=l5] for its q-row's full 64-k slice.
// P stays in registers (pk2 + shfl_xor(32)); 32x32x16 MFMA; T14 staging; T13 defer-max.
// LOAD BALANCE: cohorts z<2 / z>=2 get complementary jq (15-y vs y) so co-resident
// block pairs sum to a constant 34 k-tiles.
#define ATT_SCALE 0.08838834764831845f
#define K_LOG2E (ATT_SCALE * 1.4426950408889634f)
#define DEFER_THR 62.0f   // raw-score slack; * K_LOG2E ~= 7.9 exp2-units

__global__ __launch_bounds__(256, 2) void attn_kernel(
    const u16* __restrict__ qh, const u16* __restrict__ kh,
    const u16* __restrict__ Vt, u16* __restrict__ attn_out)
{
    __shared__ u16 Ks[64 * 128];   // 16 KiB, swizzled: row k (256B), granule^(k&7)
    __shared__ u16 Vs[128 * 64];   // 16 KiB, swizzled: row d (128B), granule^(d&7)

    const int bh = (int)blockIdx.x + ((int)blockIdx.z << 3);
    const int b = bh >> 4, h = bh & 15;
    const int jq = ((int)blockIdx.z < 2) ? (15 - (int)blockIdx.y) : (int)blockIdx.y;
    const int qbase = jq * 128;
    const int tid = threadIdx.x;
    const int lane = tid & 63;
    const int w = tid >> 6;        // 0..3
    const int l5 = lane & 31;
    const int hi = lane >> 5;
    const int wq0 = qbase + w * 32;
    const int qg = wq0 + l5;       // this lane's q-row
    const int kend = qbase + 128;
    const int kend_w = wq0 + 32;   // wave's causal limit

    // Q as B-fragments: lane holds Q[q=qg][d = kc*16 + 8*hi + j]
    bf16x8 qb[8];
    {
        const u16* qp = &qh[((long)bh * S_ + qg) * 128 + 8 * hi];
        #pragma unroll
        for (int kc = 0; kc < 8; kc++)
            qb[kc] = ld_bf8(qp + kc * 16);
    }

    f32x16 o[4] = {};     // O[d = dt*32 + (reg&3)+8*(reg>>2)+4*hi][q=qg]
    float m_run = NEG_BIG;
    float l_run = 0.f;

    const long khb = (long)bh * S_;

    // T14 staging regs: wave w loads K rows [w*16,+16), V^T d-rows [w*32,+32)
    u16x8 kst[4], vst[4];
    auto load_kv = [&](int k0) {
        #pragma unroll
        for (int it = 0; it < 4; ++it) {
            int r = w * 16 + it * 4 + (lane >> 4);
            kst[it] = *(const u16x8*)&kh[(khb + k0 + r) * 128 + (((lane & 15) ^ (r & 7)) << 3)];
        }
        #pragma unroll
        for (int it = 0; it < 4; ++it) {
            int d = w * 32 + it * 8 + (lane >> 3);
            vst[it] = *(const u16x8*)&Vt[((long)bh * 128 + d) * S_ + k0 + (((lane & 7) ^ (d & 7)) << 3)];
        }
    };

    load_kv(0);

    for (int k0 = 0; k0 < kend; k0 += 64) {
        __syncthreads();   // prev iter's LDS reads done
        #pragma unroll
        for (int it = 0; it < 4; ++it)
            *(u16x8*)&Ks[(w * 16 + it * 4) * 128 + lane * 8] = kst[it];
        #pragma unroll
        for (int it = 0; it < 4; ++it)
            *(u16x8*)&Vs[(w * 32 + it * 8) * 64 + lane * 8] = vst[it];
        __syncthreads();   // tiles visible
        if (k0 + 64 < kend) load_kv(k0 + 64);   // next tile flies under compute

        if (k0 < kend_w) {   // wave-uniform causal skip
            // ---- QK^T swapped: S[k][q], A = K rows, B = Q ----
            f32x16 sc[2] = {};
            #pragma unroll
            for (int kc = 0; kc < 8; kc++) {
                #pragma unroll
                for (int ct = 0; ct < 2; ct++) {
                    int krow = ct * 32 + l5;
                    bf16x8 kf = ld_bf8(&Ks[krow * 128 + (((2 * kc + hi) ^ (krow & 7)) << 3)]);
                    sc[ct] = __builtin_amdgcn_mfma_f32_32x32x16_bf16(kf, qb[kc], sc[ct], 0, 0, 0);
                }
            }
            // ---- causal mask (k = k0 + ct*32 + t + 8g + 4hi; col q = qg) ----
            if (k0 + 64 > wq0) {
                #pragma unroll
                for (int ct = 0; ct < 2; ct++)
                    #pragma unroll
                    for (int g = 0; g < 4; g++)
                        #pragma unroll
                        for (int t = 0; t < 4; t++)
                            sc[ct][g * 4 + t] =
                                (k0 + ct * 32 + g * 8 + t + 4 * hi <= qg) ? sc[ct][g * 4 + t] : NEG_BIG;
            }
            // ---- row max: 31 in-lane fmax + cross-half ----
            float m = sc[0][0];
            #pragma unroll
            for (int i = 1; i < 16; i++) m = fmaxf(m, sc[0][i]);
            #pragma unroll
            for (int i = 0; i < 16; i++) m = fmaxf(m, sc[1][i]);
            m = fmaxf(m, __shfl_xor(m, 32, 64));
            // ---- defer-max (T13): rescale only when some row grew >THR ----
            bool ok = (m <= m_run + DEFER_THR);
            if (!__all((int)ok)) {
                float mn = fmaxf(m_run, m);
                float alpha = exp2f((m_run - mn) * K_LOG2E);
                m_run = mn;
                l_run *= alpha;
                #pragma unroll
                for (int dt = 0; dt < 4; dt++)
                    #pragma unroll
                    for (int i = 0; i < 16; i++) o[dt][i] *= alpha;
            }
            // ---- P = exp2((S - m_run)*c) in place; in-lane sum ----
            float mk = m_run * K_LOG2E;
            float s = 0.f;
            #pragma unroll
            for (int ct = 0; ct < 2; ct++)
                #pragma unroll
                for (int i = 0; i < 16; i++) {
                    float p = exp2f(fmaf(sc[ct][i], K_LOG2E, -mk));
                    sc[ct][i] = p;
                    s += p;
                }
            l_run += s + __shfl_xor(s, 32, 64);
            // ---- build PV B-frags pb[kk = ct*2+c2]: lane needs P[k=c2*16+8hi+j][qg].
            bf16x8 pb[4];
            #pragma unroll
            for (int ct = 0; ct < 2; ct++)
                #pragma unroll
                for (int c2 = 0; c2 < 2; c2++) {
                    u32 lo0 = pk2(sc[ct][8 * c2 + 0], sc[ct][8 * c2 + 1]);
                    u32 lo1 = pk2(sc[ct][8 * c2 + 2], sc[ct][8 * c2 + 3]);
                    u32 h0  = pk2(sc[ct][8 * c2 + 4], sc[ct][8 * c2 + 5]);
                    u32 h1  = pk2(sc[ct][8 * c2 + 6], sc[ct][8 * c2 + 7]);
                    u32 s0 = hi ? lo0 : h0;
                    u32 s1 = hi ? lo1 : h1;
                    u32 r0 = (u32)__shfl_xor((int)s0, 32, 64);
                    u32 r1 = (u32)__shfl_xor((int)s1, 32, 64);
                    u32x4 f;
                    f[0] = hi ? r0 : lo0;
                    f[1] = hi ? r1 : lo1;
                    f[2] = hi ? h0 : r0;
                    f[3] = hi ? h1 : r1;
                    pb[ct * 2 + c2] = __builtin_bit_cast(bf16x8, f);
                }
            // ---- PV: O[d][q] += V^T[d][k] * P[k][q]; A = V^T rows ----
            #pragma unroll
            for (int kk = 0; kk < 4; kk++) {
                #pragma unroll
                for (int dt = 0; dt < 4; dt++) {
                    int drow = dt * 32 + l5;
                    bf16x8 vf = ld_bf8(&Vs[drow * 64 + (((2 * kk + hi) ^ (drow & 7)) << 3)]);
                    o[dt] = __builtin_amdgcn_mfma_f32_32x32x16_bf16(vf, pb[kk], o[dt], 0, 0, 0);
                }
            }
        }
    }

    // ---- epilogue: out[q=qg][d] = o/l; d = dt*32 + 8g + 4hi + t ----
    float inv = 1.0f / l_run;
    const long orow = ((long)b * S_ + qg) * 2048 + h * 128;
    #pragma unroll
    for (int dt = 0; dt < 4; dt++)
        #pragma unroll
        for (int g = 0; g < 4; g++) {
            u16x4 v;
            #pragma unroll
            for (int t = 0; t < 4; t++) v[t] = f2bf(o[dt][g * 4 + t] * inv);
            *(u16x4*)&attn_out[orow + dt * 32 + g * 8 + 4 * hi] = v;
        }
}

// ---------------- launch ----------------
#define MIB(x) ((size_t)(x) << 20)
extern "C" void kernel_launch(void* const* d_in, const int* in_sizes, int n_in,
                              void* d_out, int out_size, void* d_ws, size_t ws_size,
                              hipStream_t stream)
{
    const void* query  = d_in[0];
    const void* W_dq   = d_in[1];
    const void* W_uq   = d_in[2];
    const void* q_ln_w = d_in[3];
    const void* q_ln_b = d_in[4];
    const void* W_dkv  = d_in[5];
    const void* W_ukv  = d_in[6];
    const void* kv_ln_w = d_in[7];
    const void* kv_ln_b = d_in[8];
    const void* W_o    = d_in[9];
    (void)ws_size; (void)in_sizes; (void)n_in; (void)out_size;

    char* base = (char*)d_ws;
    u32*   flag     = (u32*)base;                         // 4 B (+pad)
    float* rope_cos = (float*)(base + 4096);              // 256 KiB
    float* rope_sin = (float*)(base + 266240);            // 256 KiB
    u16* qh     = (u16*)(base + MIB(1));                  // 16 MiB
    u16* kh     = (u16*)(base + MIB(17));                 // 16 MiB
    u16* Vt     = (u16*)(base + MIB(33));                 // 16 MiB
    u16* q_bf   = (u16*)(base + MIB(49));                 // 16 MiB
    u16* Wo_bf  = (u16*)(base + MIB(65));                 // 8 MiB
    // scratch (lifetimes): peak 134.25 MiB
    u16* Wcomb  = (u16*)(base + MIB(73));                 // 10 MiB  (prep -> gemm_down)
    u16* cqkv   = (u16*)(base + MIB(83));                 // 20 MiB  (gemm_down -> LNs)
    u16* cq     = (u16*)(base + MIB(103));                // 8 MiB   (ln -> up-Q)
    u16* kv_lat = (u16*)(base + MIB(111));                // 11 MiB  (ln -> up-KV)
    u16* WuqT   = (u16*)(base + MIB(122));                // 4 MiB
    u16* WukvT  = (u16*)(base + MIB(126));                // 8.25 MiB -> 134.25
    u16* KV     = (u16*)(base + MIB(73));                 // 24 MiB  (up-KV -> pack_vt; Wcomb/cqkv-head dead)
    u16* attn_o = (u16*)(base + MIB(73));                 // 16 MiB  (attn -> gemm_out; KV dead)

    rope_tab_kernel<<<(S_ * 32 + 255) / 256, 256, 0, stream>>>(rope_cos, rope_sin, flag);
    detect_kernel<<<64, 256, 0, stream>>>((const u16*)query, flag);

    cast_merged_kernel<<<dim3(4096, 1, 2), 256, 0, stream>>>(query, W_o, q_bf, Wo_bf, flag);
    transpose_all_kernel<<<dim3(64, 96, 4), 256, 0, stream>>>(W_dq, W_dkv, W_uq, W_ukv,
                                                              Wcomb, WuqT, WukvT, flag);

    // ---- merged down-projection GEMM ----
    gemm_bt<0><<<dim3(32, 20), 256, 0, stream>>>(q_bf, Wcomb, cqkv, MT_, NCOMB_, D_,
                                                 nullptr, nullptr, nullptr, flag);
    // ---- both LayerNorms (z=0: q, z=1: kv + out1 + roped-Kr broadcast into kh) ----
    ln_both_kernel<<<dim3(MT_, 1, 2), 256, 0, stream>>>(cqkv, q_ln_w, q_ln_b, kv_ln_w, kv_ln_b,
                                                        cq, kv_lat, d_out, kh,
                                                        rope_cos, rope_sin, flag);

    // ---- Q up-projection, fused rope+pack -> qh ----
    gemm_bt<3><<<dim3(32, 16), 256, 0, stream>>>(cq, WuqT, qh, MT_, D_, QP_,
                                                 rope_cos, rope_sin, nullptr, flag);

    // ---- KV up-projection, fused Kn -> kh, V -> KV ----
    gemm_bt<4><<<dim3(32, 24), 256, 0, stream>>>(kv_lat, WukvT, KV, MT_, UKV_N_, KVP_PAD_,
                                                 nullptr, nullptr, kh, flag);
    pack_vt_kernel<<<dim3(32, 32), 256, 0, stream>>>(KV, Vt);

    // ---- attention + out projection ----
    attn_kernel<<<dim3(8, 16, 4), 256, 0, stream>>>(qh, kh, Vt, attn_o);
    gemm_bt<2><<<dim3(32, 16), 256, 0, stream>>>(attn_o, Wo_bf, d_out, MT_, D_, D_,
                                                 nullptr, nullptr, nullptr, flag);
}